// Round 6
// baseline (260.418 us; speedup 1.0000x reference)
//
#include <hip/hip_runtime.h>
#include <stdint.h>

#define NB 8
#define CI 128
#define CO 256
#define KS 7
#define LL 16384
#define CK (CI * KS)   // 896

typedef _Float16 half8 __attribute__((ext_vector_type(8)));
typedef _Float16 half2v __attribute__((ext_vector_type(2)));
typedef float floatx4 __attribute__((ext_vector_type(4)));
typedef uint32_t uintx4 __attribute__((ext_vector_type(4)));

__device__ __forceinline__ void load16_to_lds(const void* g, void* l) {
    __builtin_amdgcn_global_load_lds(
        (const __attribute__((address_space(1))) void*)g,
        (__attribute__((address_space(3))) void*)l, 16, 0, 0);
}

// ---------- x (NB, CI, LL) f32 -> xT (NB, LL, CI) f16 ----------
__global__ __launch_bounds__(256) void convert_x(const float* __restrict__ x,
                                                 _Float16* __restrict__ xT) {
    __shared__ uint32_t tile[64][65];   // 16.6 KB
    const int n  = blockIdx.y;
    const int l0 = blockIdx.x * 64;
    const int t  = threadIdx.x;
    const float* xs = x + (size_t)n * CI * LL + l0;

    const int l4  = (t & 15) * 4;
    const int cpr = t >> 4;            // 0..15
    #pragma unroll
    for (int p = 0; p < 4; ++p) {
        const int cp = cpr + p * 16;   // c-pair 0..63
        const float4 a4 = *(const float4*)(xs + (size_t)(2 * cp) * LL + l4);
        const float4 b4 = *(const float4*)(xs + (size_t)(2 * cp + 1) * LL + l4);
        half2v h;
        h[0] = (_Float16)a4.x; h[1] = (_Float16)b4.x;
        tile[l4 + 0][cp] = __builtin_bit_cast(uint32_t, h);
        h[0] = (_Float16)a4.y; h[1] = (_Float16)b4.y;
        tile[l4 + 1][cp] = __builtin_bit_cast(uint32_t, h);
        h[0] = (_Float16)a4.z; h[1] = (_Float16)b4.z;
        tile[l4 + 2][cp] = __builtin_bit_cast(uint32_t, h);
        h[0] = (_Float16)a4.w; h[1] = (_Float16)b4.w;
        tile[l4 + 3][cp] = __builtin_bit_cast(uint32_t, h);
    }
    __syncthreads();

    const int lw  = t >> 4;            // 0..15
    const int cp0 = (t & 15) * 4;
    _Float16* xd = xT + (size_t)n * LL * CI + (size_t)l0 * CI;
    #pragma unroll
    for (int p = 0; p < 4; ++p) {
        const int l = lw + p * 16;
        uintx4 d;
        d[0] = tile[l][cp0 + 0];
        d[1] = tile[l][cp0 + 1];
        d[2] = tile[l][cp0 + 2];
        d[3] = tile[l][cp0 + 3];
        *(uintx4*)(xd + (size_t)l * CI + cp0 * 2) = d;
    }
}

// ---------- w (CO, CI, KS) f32 -> wT (CO, KS*CI) f16 ck-order, + 128-half zero row ----------
__global__ __launch_bounds__(256) void convert_w(const float* __restrict__ w,
                                                 _Float16* __restrict__ wT) {
    const int t = blockIdx.x * 256 + threadIdx.x;
    if (t >= CO * CK + 128) return;
    if (t >= CO * CK) { wT[t] = (_Float16)0.f; return; }
    const int o = t / CK;
    const int r = t - o * CK;
    const int k = r >> 7;
    const int c = r & 127;
    wT[t] = (_Float16)w[(size_t)o * CK + c * KS + k];
}

// ---------- MFMA GEMM: 256l x 256o tile, 8 waves, 4-phase/K-step (m201 port) ----------
// o-merged: each block computes ALL CO=256 for its 256-l slice -> gather once.
// Per K-step (BK=64): 4 phases {ds_read subtile; stage 2 next-step loads;
// barrier; lgkm(0); setprio+16 MFMA; barrier}.  B (gather, long latency) staged
// in ph0/ph1; A (L2-hot wT) in ph2/ph3; one vmcnt(0) per step after ph3 MFMA.
// XOR chunk-swizzle (proven conflict-free): LDS linear, source pre-swizzled,
// ds_read applies same involution.
__global__ __launch_bounds__(512, 2) void iconv_mfma(
    const _Float16* __restrict__ xT,   // (NB, LL, CI)
    const int*      __restrict__ idx,  // (KS, LL), -1 = masked
    const _Float16* __restrict__ wT,   // (CO, CK)
    const float*    __restrict__ bias, // (CO)
    const _Float16* __restrict__ zrow, // 128 halfs of zeros
    float*          __restrict__ out)  // (NB, CO, LL)
{
    __shared__ _Float16 a_lds[2][256 * 64];   // 2 x 32 KB
    __shared__ _Float16 b_lds[2][256 * 64];   // 2 x 32 KB  (total 128 KiB)

    const int l0 = blockIdx.x * 256;
    const int n  = blockIdx.z;
    const int t  = threadIdx.x;
    const int lane = t & 63;
    const int wv  = t >> 6;            // 0..7
    const int wo  = (wv >> 2) * 128;   // o-offset of wave tile (128 rows)
    const int wl  = (wv & 3) * 64;     // l-offset of wave tile (64 cols)
    const int m16 = lane & 15;
    const int l4g = lane >> 4;         // 0..3
    const int swz = m16 & 7;
    const int ch0 = (l4g ^ swz) * 8;        // kk=0 swizzled chunk (halfs)
    const int ch1 = ((4 + l4g) ^ swz) * 8;  // kk=1

    floatx4 acc[8][4];
    #pragma unroll
    for (int i = 0; i < 8; ++i)
        #pragma unroll
        for (int j = 0; j < 4; ++j) acc[i][j] = (floatx4)0.f;

    // staging geometry: 256 rows x 128 B per operand; chunk c = j*512 + t
    const int rrow = t >> 3;                   // 0..63
    const int part = t & 7;
    const int sp   = (part ^ (rrow & 7)) * 8;  // swizzled SOURCE offset (halfs)
    const int dstb = rrow * 64 + part * 8;     // LINEAR LDS dest; + j*4096

    // prefetch all gather indices to regs
    int iv[KS][4];
    #pragma unroll
    for (int k = 0; k < KS; ++k)
        #pragma unroll
        for (int j = 0; j < 4; ++j)
            iv[k][j] = idx[k * LL + l0 + j * 64 + rrow];

    const _Float16* xbase = xT + (size_t)n * LL * CI;
    const _Float16* abase = wT + (size_t)rrow * CK + sp;

    // ---- prologue: stage step 0 (k=0, c0=0) fully, drain, barrier
    #pragma unroll
    for (int j = 0; j < 4; ++j) {
        const int ii = iv[0][j];
        const _Float16* bs = (ii >= 0) ? (xbase + (size_t)ii * CI + sp)
                                       : (zrow + sp);
        load16_to_lds(bs, &b_lds[0][j * 4096 + dstb]);
        load16_to_lds(abase + (size_t)j * 64 * CK, &a_lds[0][j * 4096 + dstb]);
    }
    asm volatile("s_waitcnt vmcnt(0)" ::: "memory");
    __builtin_amdgcn_s_barrier();

#define RD_A(mh, ch)                                                              \
    af[0] = *(const half8*)(&a_lds[cur][(wo + (mh)*64 +  0 + m16) * 64 + (ch)]);  \
    af[1] = *(const half8*)(&a_lds[cur][(wo + (mh)*64 + 16 + m16) * 64 + (ch)]);  \
    af[2] = *(const half8*)(&a_lds[cur][(wo + (mh)*64 + 32 + m16) * 64 + (ch)]);  \
    af[3] = *(const half8*)(&a_lds[cur][(wo + (mh)*64 + 48 + m16) * 64 + (ch)]);

#define RD_B(ch)                                                                  \
    bf[0] = *(const half8*)(&b_lds[cur][(wl +  0 + m16) * 64 + (ch)]);            \
    bf[1] = *(const half8*)(&b_lds[cur][(wl + 16 + m16) * 64 + (ch)]);            \
    bf[2] = *(const half8*)(&b_lds[cur][(wl + 32 + m16) * 64 + (ch)]);            \
    bf[3] = *(const half8*)(&b_lds[cur][(wl + 48 + m16) * 64 + (ch)]);

#define STG_B(jj) do {                                                            \
    const int ii = iv[k1][jj];                                                    \
    const _Float16* bs = (ii >= 0) ? (xbase + (size_t)ii * CI + c1 + sp)          \
                                   : (zrow + c1 + sp);                            \
    load16_to_lds(bs, &b_lds[nb][(jj) * 4096 + dstb]); } while (0)

#define STG_A(jj)                                                                 \
    load16_to_lds(abase + (size_t)(jj) * 64 * CK + k1 * CI + c1,                  \
                  &a_lds[nb][(jj) * 4096 + dstb])

#define MFMA16(mh)                                                                \
    __builtin_amdgcn_s_setprio(1);                                                \
    _Pragma("unroll")                                                             \
    for (int mf = 0; mf < 4; ++mf)                                                \
        _Pragma("unroll")                                                         \
        for (int nf = 0; nf < 4; ++nf)                                            \
            acc[(mh)*4 + mf][nf] = __builtin_amdgcn_mfma_f32_16x16x32_f16(        \
                af[mf], bf[nf], acc[(mh)*4 + mf][nf], 0, 0, 0);                   \
    __builtin_amdgcn_s_setprio(0);

#define PH_SYNC                                                                   \
    __builtin_amdgcn_s_barrier();                                                 \
    asm volatile("s_waitcnt lgkmcnt(0)" ::: "memory");                            \
    __builtin_amdgcn_sched_barrier(0);

    #pragma unroll
    for (int s = 0; s < 2 * KS; ++s) {
        const int cur = s & 1;
        const int k1  = (s + 1) >> 1;          // next step k
        const int c1  = ((s + 1) & 1) * 64;    // next step c0
        const int nb  = (s + 1) & 1;           // next step buffer
        half8 af[4], bf[4];

        // ---- ph0: af(mfh0,kk0)+bf(kk0); stage next-B j0,j1
        RD_A(0, ch0) RD_B(ch0)
        if (s < 2 * KS - 1) { STG_B(0); STG_B(1); }
        PH_SYNC
        MFMA16(0)
        __builtin_amdgcn_s_barrier();

        // ---- ph1: af(mfh1,kk0); stage next-B j2,j3  (bf persists)
        RD_A(1, ch0)
        if (s < 2 * KS - 1) { STG_B(2); STG_B(3); }
        PH_SYNC
        MFMA16(1)
        __builtin_amdgcn_s_barrier();

        // ---- ph2: af(mfh0,kk1)+bf(kk1); stage next-A j0,j1
        RD_A(0, ch1) RD_B(ch1)
        if (s < 2 * KS - 1) { STG_A(0); STG_A(1); }
        PH_SYNC
        MFMA16(0)
        __builtin_amdgcn_s_barrier();

        // ---- ph3: af(mfh1,kk1); stage next-A j2,j3; vmcnt(0) once per step
        RD_A(1, ch1)
        if (s < 2 * KS - 1) { STG_A(2); STG_A(3); }
        PH_SYNC
        MFMA16(1)
        if (s < 2 * KS - 1)
            asm volatile("s_waitcnt vmcnt(0)" ::: "memory");
        __builtin_amdgcn_s_barrier();
    }

#undef RD_A
#undef RD_B
#undef STG_A
#undef STG_B
#undef MFMA16
#undef PH_SYNC

    // epilogue: D[m][n]: o=(lane>>4)*4+reg within frag, l=lane&15
    const int r4 = (lane >> 4) * 4;
    #pragma unroll
    for (int mf = 0; mf < 8; ++mf) {
        const int obase = wo + mf * 16 + r4;
        const floatx4 b4 = *(const floatx4*)(bias + obase);
        #pragma unroll
        for (int nf = 0; nf < 4; ++nf) {
            const int l = l0 + wl + nf * 16 + m16;
            float* op = out + ((size_t)n * CO + obase) * LL + l;
            #pragma unroll
            for (int r = 0; r < 4; ++r)
                op[(size_t)r * LL] = acc[mf][nf][r] + b4[r];
        }
    }
}

// ---------- fp32 fallback (only if workspace too small) ----------
__global__ __launch_bounds__(256) void iconv_fallback(
    const float* __restrict__ x, const int* __restrict__ idx,
    const float* __restrict__ w, const float* __restrict__ bias,
    float* __restrict__ out)
{
    __shared__ float col[CI][64];
    const int n  = blockIdx.y;
    const int l0 = blockIdx.x * 64;
    const int t  = threadIdx.x;
    const int ot = t & 63, lt = t >> 6;
    const int j = t >> 2, part = t & 3;
    float acc[4][16];
    #pragma unroll
    for (int oo = 0; oo < 4; ++oo) {
        const float bv = bias[ot * 4 + oo];
        #pragma unroll
        for (int ll = 0; ll < 16; ++ll) acc[oo][ll] = bv;
    }
    for (int k = 0; k < KS; ++k) {
        __syncthreads();
        const int i = idx[k * LL + l0 + j];
        const float* xr = x + (size_t)n * CI * LL;
        for (int q = 0; q < 32; ++q) {
            const int c = part * 32 + q;
            col[c][j] = (i >= 0) ? xr[(size_t)c * LL + i] : 0.f;
        }
        __syncthreads();
        for (int c = 0; c < CI; ++c) {
            const float* bv = &col[c][lt * 16];
            float wv[4];
            #pragma unroll
            for (int oo = 0; oo < 4; ++oo)
                wv[oo] = w[(size_t)(ot * 4 + oo) * CK + c * KS + k];
            #pragma unroll
            for (int oo = 0; oo < 4; ++oo)
                #pragma unroll
                for (int ll = 0; ll < 16; ++ll)
                    acc[oo][ll] += wv[oo] * bv[ll];
        }
    }
    #pragma unroll
    for (int oo = 0; oo < 4; ++oo) {
        float* orow = out + ((size_t)n * CO + (ot * 4 + oo)) * LL + l0 + lt * 16;
        #pragma unroll
        for (int q = 0; q < 16; ++q) orow[q] = acc[oo][q];
    }
}

extern "C" void kernel_launch(void* const* d_in, const int* in_sizes, int n_in,
                              void* d_out, int out_size, void* d_ws, size_t ws_size,
                              hipStream_t stream) {
    const float* x    = (const float*)d_in[0];
    const int*   idx  = (const int*)d_in[1];
    const float* w    = (const float*)d_in[2];
    const float* bias = (const float*)d_in[3];
    float* out = (float*)d_out;

    const size_t xt_bytes = (size_t)NB * LL * CI * sizeof(_Float16);     // 32 MiB
    const size_t wt_elems = (size_t)CO * CK + 128;                       // incl. zero row
    const size_t need = xt_bytes + wt_elems * sizeof(_Float16);

    if (ws_size >= need) {
        _Float16* xT = (_Float16*)d_ws;
        _Float16* wT = (_Float16*)((char*)d_ws + xt_bytes);
        const _Float16* zr = wT + (size_t)CO * CK;
        convert_x<<<dim3(LL / 64, NB), 256, 0, stream>>>(x, xT);
        convert_w<<<dim3(((int)wt_elems + 255) / 256), 256, 0, stream>>>(w, wT);
        iconv_mfma<<<dim3(LL / 256, 1, NB), 512, 0, stream>>>(
            xT, idx, wT, bias, zr, out);
    } else {
        iconv_fallback<<<dim3(LL / 64, NB), 256, 0, stream>>>(x, idx, w, bias, out);
    }
}